// Round 9
// baseline (665.026 us; speedup 1.0000x reference)
//
#include <hip/hip_runtime.h>
#include <math.h>

#define V96 (96*96*96)
#define NDIVBLK 3350   // ceil(95^3/256)
#define NMEDBLK 3456   // 3*48*24

#define KSENT 0x7FFFFFFF  // int-key sentinel, > key(+inf)=0x7F800000

// ---------- helpers ----------

__device__ __forceinline__ int reflect_idx(int t, int n) {
  if (t < 0) t = -t;
  if (t >= n) t = 2 * n - 2 - t;
  return t;
}

// Monotone float<->signed-int key transform (involution).
__device__ __forceinline__ int fkey(float f) {
  int b = __float_as_int(f);
  return b ^ ((b >> 31) & 0x7FFFFFFF);
}
__device__ __forceinline__ float funkey(int k) {
  return __int_as_float(k ^ ((k >> 31) & 0x7FFFFFFF));
}

__device__ __forceinline__ void cswap(int& a, int& b) {
  int lo = min(a, b);
  int hi = max(a, b);
  a = lo;
  b = hi;
}

// Batcher odd-even mergesort on v[0..N), N power of 2. Fully unrolled.
template <int N>
__device__ __forceinline__ void sortn(int* v) {
#pragma unroll
  for (int p = 1; p < N; p <<= 1) {
#pragma unroll
    for (int k = p; k >= 1; k >>= 1) {
#pragma unroll
      for (int j = k % p; j <= N - 1 - k; j += 2 * k) {
#pragma unroll
        for (int i = 0; i < k; i++) {
          if (i + j + k <= N - 1) {
            if ((i + j) / (2 * p) == (i + j + k) / (2 * p)) {
              cswap(v[i + j], v[i + j + k]);
            }
          }
        }
      }
    }
  }
}

// 256-thread block: reduce val; result valid on tid 0.
__device__ __forceinline__ double block_reduce_sum(double val, double* sh) {
  int tid = threadIdx.x;
  int lane = tid & 63;
  int wv = tid >> 6;
#pragma unroll
  for (int off = 32; off > 0; off >>= 1) val += __shfl_down(val, off, 64);
  if (lane == 0) sh[wv] = val;
  __syncthreads();
  double r = 0.0;
  if (tid == 0) {
#pragma unroll
    for (int i = 0; i < 4; i++) r += sh[i];
  }
  return r;
}

// 512-thread block: reduce val; result valid on tid 0. sh[8].
__device__ __forceinline__ double block_reduce_sum8(double val, double* sh) {
  int tid = threadIdx.x;
  int lane = tid & 63;
  int wv = tid >> 6;
#pragma unroll
  for (int off = 32; off > 0; off >>= 1) val += __shfl_down(val, off, 64);
  if (lane == 0) sh[wv] = val;
  __syncthreads();
  double r = 0.0;
  if (tid == 0) {
#pragma unroll
    for (int i = 0; i < 8; i++) r += sh[i];
  }
  return r;
}

// ---------- stage 1: masked fields ----------

__global__ __launch_bounds__(256) void prep_mask_kernel(
    const float* __restrict__ pred_b, const float* __restrict__ targets,
    float* __restrict__ bxm, float* __restrict__ bym) {
  int i = blockIdx.x * 256 + threadIdx.x;
  if (i >= V96) return;
  float bxp = pred_b[i];
  float byp = pred_b[V96 + i];
  float bxt = targets[i];
  float byt = targets[V96 + i];
  float m = (bxp * bxt + byp * byt > 0.0f) ? 1.0f : -1.0f;
  bxm[i] = bxt * m;
  bym[i] = byt * m;
}

// ---------- stage 2: fused div-c flux reduction (2 x 95^3 cells) ----------

__global__ __launch_bounds__(256) void div_fused_kernel(
    const float* __restrict__ pbx, const float* __restrict__ pby,
    const float* __restrict__ bxm, const float* __restrict__ bym,
    const float* __restrict__ bz, const float* __restrict__ z,
    double* __restrict__ P) {
  __shared__ double sh1[4];
  __shared__ double sh2[4];
  const int N = 95 * 95 * 95;
  int which = (blockIdx.x >= NDIVBLK) ? 1 : 0;
  int blk = blockIdx.x - which * NDIVBLK;
  const float* bx = which ? bxm : pbx;
  const float* by = which ? bym : pby;
  int idx = blk * 256 + threadIdx.x;
  double fs = 0.0, fq = 0.0;
  if (idx < N) {
    int w = idx % 95;
    int t = idx / 95;
    int h = t % 95;
    int d = t / 95;
    int o = (d * 96 + h) * 96 + w;
#define LD8(A, p)                                                             \
  float A##000 = p[o], A##001 = p[o + 1], A##010 = p[o + 96],                 \
        A##011 = p[o + 97], A##100 = p[o + 9216], A##101 = p[o + 9217],       \
        A##110 = p[o + 9312], A##111 = p[o + 9313];
    LD8(bxv, bx)
    LD8(byv, by)
    LD8(bzv, bz)
    LD8(zv, z)
#undef LD8
    float az1 = fabsf(zv001 - zv000);
    float az2 = fabsf(zv011 - zv010);
    float az3 = fabsf(zv101 - zv100);
    float az4 = fabsf(zv111 - zv110);
    const float c6 = 1.0f / 6.0f;
    const float c3 = 1.0f / 3.0f;
    float flux =
        0.25f * (bxv100 + bxv110 + bxv101 + bxv111) * 0.5f * (az3 + az4) -
        0.25f * (bxv000 + bxv010 + bxv001 + bxv011) * 0.5f * (az1 + az2) +
        0.25f * (byv010 + byv110 + byv011 + byv111) * 0.5f * (az2 + az4) -
        0.25f * (byv000 + byv100 + byv001 + byv101) * 0.5f * (az1 + az3) +
        0.5f * ((bzv001 + bzv101 + bzv111) + (bzv001 + bzv111 + bzv011)) * c3 -
        0.5f * ((bzv000 + bzv100 + bzv110) + (bzv000 + bzv110 + bzv010)) * c3 +
        (bxv001 + bxv101 + bxv111) * (zv001 - zv101) * c6 +
        (bxv001 + bxv011 + bxv111) * (zv011 - zv111) * c6 +
        (byv001 + byv101 + byv111) * (zv101 - zv111) * c6 +
        (byv001 + byv011 + byv111) * (zv001 - zv011) * c6 -
        ((bxv000 + bxv100 + bxv110) * (zv000 - zv100) * c6 +
         (bxv000 + bxv010 + bxv110) * (zv010 - zv110) * c6 +
         (byv000 + byv100 + byv110) * (zv100 - zv110) * c6 +
         (byv000 + byv010 + byv110) * (zv000 - zv010) * c6);
    float sbx = bxv000 + bxv001 + bxv010 + bxv011 + bxv100 + bxv101 + bxv110 +
                bxv111;
    float sby = byv000 + byv001 + byv010 + byv011 + byv100 + byv101 + byv110 +
                byv111;
    float sbz = bzv000 + bzv001 + bzv010 + bzv011 + bzv100 + bzv101 + bzv110 +
                bzv111;
    float ave = 0.015625f * (sbx * sbx + sby * sby + sbz * sbz) + 1e-8f;
    float res = flux * flux;
    float flx1 = res * res / ave;
    fs = (double)flx1;
    fq = (double)flx1 * (double)flx1;
  }
  double bs = block_reduce_sum(fs, sh1);
  double bq = block_reduce_sum(fq, sh2);
  if (threadIdx.x == 0) {
    P[(which ? 2 : 0) * NDIVBLK + blk] = bs;
    P[(which ? 3 : 1) * NDIVBLK + blk] = bq;
  }
}

// ---------- stage 3: FUSED median, PAIR-SPLIT: 2 threads per voxel ----------
// 512-thread block covers a 32x2x4 voxel tile (256 voxels x 2 threads).
// Even lane sorts window elems 0..63; odd lane sorts 64..124 + 3 sentinels;
// rank-62-of-union select runs via 32 __shfl_xor(.,1) exchanges, half the
// terms per lane. Peak liveness ~75 regs -> no AGPR traffic at the 85-reg
// cap of __launch_bounds__(512,6); LDS = tile only (~7 KB) -> 24 waves/CU.
// fid 0: jx (96,95,95)  1: jy (95,96,95)  2: jz (95,95,96)
// fid 3..6: plain bxm,bym,pbx,pby (96^3)

__global__ __launch_bounds__(512, 6) void med_fused_kernel(
    const float* __restrict__ bxm, const float* __restrict__ bym,
    const float* __restrict__ pbx, const float* __restrict__ pby,
    const float* __restrict__ bzp, double* __restrict__ part) {
  __shared__ int tile[8][6][36];
  __shared__ double sh[8];

  const int gz = blockIdx.z;
  const int fid = gz / 24;        // 0..6, uniform
  const int zb = gz - fid * 24;   // 0..23
  const int W = (fid == 0 || fid == 1) ? 95 : 96;
  const int H = (fid == 0 || fid == 2) ? 95 : 96;
  const int D = (fid == 1 || fid == 2) ? 95 : 96;

  const int w0 = blockIdx.x * 32;
  const int h0 = blockIdx.y * 2;
  const int d0 = zb * 4;
  const int tid = threadIdx.x;        // 0..511
  const int v = tid >> 1;             // voxel 0..255
  const int vx = v & 31;              // w offset
  const int vy = (v >> 5) & 1;        // h offset
  const int vz = v >> 6;              // d offset
  const bool isA = ((tid & 1) == 0);

  const float* fplain =
      (fid == 3) ? bxm : (fid == 4) ? bym : (fid == 5) ? pbx : pby;

  for (int il = tid; il < 8 * 6 * 36; il += 512) {
    int lw = il % 36;
    int lh = (il / 36) % 6;
    int ld = il / 216;
    int gw = reflect_idx(w0 + lw - 2, W);
    int gh = reflect_idx(h0 + lh - 2, H);
    int gd = reflect_idx(d0 + ld - 2, D);
    float val;
    if (fid >= 3) {
      val = fplain[(gd * H + gh) * W + gw];
    } else {
      int o = (gd * 96 + gh) * 96 + gw;
      if (fid == 0) {
        val = 0.5f * ((bzp[o] - bzp[o + 96] + bzp[o + 1] - bzp[o + 97]) -
                      (bym[o] - bym[o + 1] + bym[o + 96] - bym[o + 97]));
      } else if (fid == 1) {
        val = 0.5f *
              ((bxm[o] - bxm[o + 1] + bxm[o + 9216] - bxm[o + 9217]) -
               (bzp[o] - bzp[o + 9216] + bzp[o + 1] - bzp[o + 9217]));
      } else {
        val = 0.5f *
              ((bym[o] - bym[o + 9216] + bym[o + 96] - bym[o + 9312]) -
               (bxm[o] - bxm[o + 96] + bxm[o + 9216] - bxm[o + 9312]));
      }
    }
    tile[ld][lh][lw] = fkey(val);
  }
  __syncthreads();

  // window element r -> (i,j,l) = (r/25, (r/5)%5, r%5)
#define TW(r) tile[vz + (r) / 25][vy + ((r) / 5) % 5][vx + (r) % 5]

  // ---- load + sort my half (common sort code, divergent loads only) ----
  int V[64];
  if (isA) {
#pragma unroll
    for (int r = 0; r < 64; r++) V[r] = TW(r);
  } else {
#pragma unroll
    for (int r = 64; r < 125; r++) V[r - 64] = TW(r);
    V[61] = KSENT;
    V[62] = KSENT;
    V[63] = KSENT;
  }
  sortn<64>(V);

  int ckey = tile[vz + 2][vy + 2][vx + 2];
#undef TW

  // ---- select rank 62 (0-based) of the 128-union via pair exchange ----
  // med = min(B[62], A[62], min_{i=1..62} max(A[i-1], B[62-i]));
  // B[61],B[62] are sentinels so terms i=0,1 drop out automatically.
  // A-lane handles i=1..31 (needs B[61-j], j=0..30);
  // B-lane handles i=32..62 (needs A[31+j], j=0..30) and i=63 (A[62], j=31).
  int acc = KSENT;
#pragma unroll
  for (int j = 0; j <= 31; j++) {
    int send = isA ? V[31 + j] : V[61 - j];
    int got = __shfl_xor(send, 1, 64);
    if (j <= 30) {
      int mine = isA ? V[j] : V[30 - j];
      acc = min(acc, max(mine, got));
    } else {
      if (!isA) acc = min(acc, got);  // i=63 term: A[62]
    }
  }
  int other = __shfl_xor(acc, 1, 64);
  int mk = min(acc, other);

  float dlt = funkey(mk) - funkey(ckey);
  const int w = w0 + vx;
  const int h = h0 + vy;
  const int d = d0 + vz;
  double c =
      (isA && w < W && h < H && d < D) ? (double)dlt * (double)dlt : 0.0;
  double bs = block_reduce_sum8(c, sh);
  if (tid == 0) {
    part[fid * NMEDBLK + blockIdx.x + 3 * (blockIdx.y + 48 * zb)] = bs;
  }
}

// ---------- stage 4: reduce partials, finalize 6 scalars ----------

__global__ __launch_bounds__(256) void finalize_kernel(
    const double* __restrict__ P, float* __restrict__ out) {
  __shared__ double sh[4];
  __shared__ double res[11];
  int tid = threadIdx.x;
  for (int q = 0; q < 11; q++) {
    const double* base =
        (q < 4) ? (P + q * NDIVBLK) : (P + 4 * NDIVBLK + (q - 4) * NMEDBLK);
    int cnt = (q < 4) ? NDIVBLK : NMEDBLK;
    double s = 0.0;
    for (int i = tid; i < cnt; i += 256) s += base[i];
#pragma unroll
    for (int off = 32; off > 0; off >>= 1) s += __shfl_down(s, off, 64);
    if ((tid & 63) == 0) sh[tid >> 6] = s;
    __syncthreads();
    if (tid == 0) res[q] = sh[0] + sh[1] + sh[2] + sh[3];
    __syncthreads();
  }
  if (tid == 0) {
    const double Nd = 95.0 * 95.0 * 95.0;
    const double Nj = 96.0 * 95.0 * 95.0;
    const double Nv = 96.0 * 96.0 * 96.0;
    double mp = res[0] / Nd;
    double mt = res[2] / Nd;
    out[0] = (float)mp;
    out[1] = (float)(res[1] / Nd - mp * mp);
    out[2] = (float)mt;
    out[3] = (float)(res[3] / Nd - mt * mt);
    out[4] = (float)((res[4] + res[5] + res[6]) / Nj);
    out[5] = (float)((res[7] + res[8] + res[9] + res[10]) / Nv);
  }
}

// ---------- launcher ----------

extern "C" void kernel_launch(void* const* d_in, const int* in_sizes, int n_in,
                              void* d_out, int out_size, void* d_ws,
                              size_t ws_size, hipStream_t stream) {
  (void)in_sizes;
  (void)n_in;
  (void)out_size;
  (void)ws_size;
  const float* pred_b = (const float*)d_in[0];
  const float* pred_z = (const float*)d_in[1];
  const float* targets = (const float*)d_in[2];
  float* out = (float*)d_out;

  double* P = (double*)d_ws;                     // 4*NDIVBLK + 7*NMEDBLK doubles
  size_t pdoubles = 4 * NDIVBLK + 7 * NMEDBLK;
  float* bxm = (float*)(P + pdoubles);
  float* bym = bxm + V96;

  const float* bzt = targets + 2 * V96;
  const float* pbx = pred_b;
  const float* pby = pred_b + V96;
  const float* bzp = pred_b + 2 * V96;

  prep_mask_kernel<<<dim3((V96 + 255) / 256), dim3(256), 0, stream>>>(
      pred_b, targets, bxm, bym);

  div_fused_kernel<<<dim3(2 * NDIVBLK), dim3(256), 0, stream>>>(
      pbx, pby, bxm, bym, bzt, pred_z, P);

  double* M = P + 4 * NDIVBLK;
  med_fused_kernel<<<dim3(3, 48, 24 * 7), dim3(512), 0, stream>>>(
      bxm, bym, pbx, pby, bzp, M);

  finalize_kernel<<<1, 256, 0, stream>>>(P, out);
}